// Round 12
// baseline (130.855 us; speedup 1.0000x reference)
//
#include <hip/hip_runtime.h>

// FirUpsample R11 = R8 skeleton + COALESCED x-gather.
// Root-cause model (fits R3-R10): the strided-scalar x staging (8 ic/thread at
// 16KB stride) makes every lane of every stage-load touch its own cache line:
// ~2880 lines/chunk/block. R8 (4 reps re-gather, 1 blk/CU) = ~184k lines/CU
// ~ 77us of L1 line serialization -- the invariant ~105-135us across rounds.
// R11 stages x as aligned float4 ROW loads (unit = (ic, gh-row, f4-of-4-gw)):
// 480 lines/chunk (6x fewer); transpose happens on the LDS-write side as
// 4x ds_write_b16 (~4-way conflicts, cheap). A = w bf16 stays LDS-resident
// (one-time coalesced preload, R8-verified). Math/partition/epilogue = R8.

typedef short bf16x8 __attribute__((ext_vector_type(8)));
typedef short short4v __attribute__((ext_vector_type(4)));
typedef float f32x16 __attribute__((ext_vector_type(16)));
typedef float f32x4v __attribute__((ext_vector_type(4)));

static __device__ __forceinline__ short f2bf(float f) {
  union { float f; unsigned u; } v; v.f = f;
  unsigned r = (v.u + 0x7FFFu + ((v.u >> 16) & 1u)) >> 16;
  return (short)r;
}
static __device__ __forceinline__ float bf2f(short s) {
  union { unsigned u; float f; } v; v.u = ((unsigned)(unsigned short)s) << 16;
  return v.f;
}

#define XS_OFF 147456
#define XS_SZ  5760

__global__ __launch_bounds__(512, 1)
void fir_up_v11(const float* __restrict__ x, const float* __restrict__ w,
                float* __restrict__ out) {
  __shared__ __align__(16) char smem[160256];
  char* Ab = smem;

  const int bid = blockIdx.x;
  const int octile = bid & 7;          // XCD bid&7 owns one octile's w-slice
  const int atile = (bid >> 3) & 7;
  const int n = bid >> 6;              // 0..3
  const int A0 = atile * 8;

  const int tid = threadIdx.x;
  const int wid = tid >> 6;
  const int lane = tid & 63;
  const int l31 = lane & 31, q = lane >> 5;
  const int swzA = (l31 & 7) << 4;

  // ---- one-time preload: w slice (32 oc x 256 ic x 9) -> As, coalesced (R8) ----
  for (int r = 0; r < 36; ++r) {
    const int f = tid + r * 512;
    const int oc = f / 576;
    const int rem = f - oc * 576;
    const f32x4v v = *(const f32x4v*)(w + (size_t)(octile * 32 + oc) * 2304 + rem * 4);
#pragma unroll
    for (int e = 0; e < 4; ++e) {
      const int flat = rem * 4 + e;
      const int ic = flat / 9;
      const int kq = flat - ic * 9;
      const int byte = (kq * 16384 + oc * 512 + ic * 2) ^ ((oc & 7) << 4);
      *(short*)(Ab + byte) = f2bf(v[e]);
    }
  }

  // ---- plane geometry & per-wave partition (verbatim R8, verified) ----
  const int COLSt[4]  = {17, 18, 17, 18};
  const int CELLSt[4] = {153, 162, 170, 180};
  const int NKt[4]    = {4, 2, 2, 1};
  const int KQt[4][4] = {{0,2,6,8},{1,7,7,7},{3,5,5,5},{4,4,4,4}};
  const int DYt[4][4] = {{0,0,1,1},{0,1,1,1},{0,0,0,0},{0,0,0,0}};
  const int DXt[4][4] = {{0,1,0,1},{0,0,0,0},{0,1,1,1},{0,0,0,0}};
  const int SEG0P[8]   = {0,0,0,1,1,2,2,3};
  const int SEG0FGB[8] = {0,2,4,0,3,0,3,0};
  const int SEG0NFG[8] = {2,2,1,3,3,3,3,4};

  const int p0w = SEG0P[wid];
  const int nk0 = NKt[p0w];
  const int nfg0 = SEG0NFG[wid];
  int aoff0[4];
#pragma unroll
  for (int s = 0; s < 4; ++s) aoff0[s] = KQt[p0w][s] * 16384 + l31 * 512 + q * 16;
  int bcell0[4][4], valid0[4], hbase0[4];
#pragma unroll
  for (int fg = 0; fg < 4; ++fg) {
    const int cellraw = (SEG0FGB[wid] + fg) * 32 + l31;
    const int valid = cellraw < CELLSt[p0w];
    const int cell = valid ? cellraw : 0;
    const int cols = COLSt[p0w];
    const int r = cell / cols;
    const int c = cell - r * cols;
    valid0[fg] = valid;
    hbase0[fg] = p0w * 1600 + r * 20 + c;
#pragma unroll
    for (int s = 0; s < 4; ++s)
      bcell0[fg][s] = (r + DYt[p0w][s]) * 18 + (c + DXt[p0w][s]);
  }
  const int aoff1 = 4 * 16384 + l31 * 512 + q * 16;
  int bcell1[2], valid1[2], hbase1[2];
#pragma unroll
  for (int j = 0; j < 2; ++j) {
    const int cellraw = (4 + j) * 32 + l31;
    const int valid = cellraw < 180;
    const int cell = valid ? cellraw : 0;
    const int r = cell / 18;
    const int c = cell - r * 18;
    valid1[j] = valid;
    hbase1[j] = 3 * 1600 + r * 20 + c;
    bcell1[j] = r * 18 + c;
  }

  // ---- x-stage unit decode (btile-invariant): units u in [0,960) ----
  // u = f4g*160 + gh*16 + ic  (ic-minor -> write banks spread)
  int f4g_[2], gh_[2], ic_[2], ghg_[2];
  bool rowok_[2], act_[2];
#pragma unroll
  for (int t = 0; t < 2; ++t) {
    const int u = tid + t * 512;
    act_[t] = u < 960;
    const int uu = act_[t] ? u : 0;
    f4g_[t] = uu / 160;
    const int rem = uu - f4g_[t] * 160;
    gh_[t] = rem >> 4;
    ic_[t] = rem & 15;
    ghg_[t] = A0 - 1 + gh_[t];
    rowok_[t] = (ghg_[t] >= 0) & (ghg_[t] < 64);
  }

  __syncthreads();  // As ready

  const float kf4[4] = {0.25f, 0.75f, 0.75f, 0.25f};

  // ---- btile reps: 4 x (K-loop over 16 ic-chunks + FIR epilogue) ----
  for (int btile = 0; btile < 4; ++btile) {
    const int B0 = btile * 16;
    int gw0_[2]; bool al_[2];
#pragma unroll
    for (int t = 0; t < 2; ++t) {
      gw0_[t] = B0 - 4 + 4 * f4g_[t];
      al_[t] = (gw0_[t] >= 0) & (gw0_[t] <= 60);
    }

    f32x16 acc[4];
#pragma unroll
    for (int fg = 0; fg < 4; ++fg)
#pragma unroll
      for (int e = 0; e < 16; ++e) acc[fg][e] = 0.f;

    // prologue: stage chunk 0 -> xs half 0 (full stall, once per rep)
    {
      short* xsw = (short*)(smem + XS_OFF);
#pragma unroll
      for (int t = 0; t < 2; ++t) {
        if (act_[t]) {
          float v[4] = {0.f, 0.f, 0.f, 0.f};
          if (rowok_[t]) {
            const float* base = x + (((size_t)(n * 256 + ic_[t]) * 64 + ghg_[t]) * 64);
            if (al_[t]) {
              const f32x4v fv = *(const f32x4v*)(base + gw0_[t]);
#pragma unroll
              for (int e = 0; e < 4; ++e) v[e] = fv[e];
            } else {
#pragma unroll
              for (int e = 0; e < 4; ++e) {
                const int gwe = gw0_[t] + e;
                v[e] = (gwe >= 0 && gwe < 64) ? base[gwe] : 0.f;
              }
            }
          }
#pragma unroll
          for (int e = 0; e < 4; ++e) {
            const int ww = f4g_[t] * 4 + e - 3;
            if (ww >= 0 && ww < 18)
              xsw[(gh_[t] * 18 + ww) * 16 + ic_[t]] = f2bf(v[e]);
          }
        }
      }
    }
    __syncthreads();

    for (int cc = 0; cc < 16; ++cc) {
      char* xr = smem + XS_OFF + (cc & 1) * XS_SZ;
      short* xw = (short*)(smem + XS_OFF + ((cc & 1) ^ 1) * XS_SZ);

      // issue next chunk's loads early (hide under MFMA)
      float v0[4] = {0.f, 0.f, 0.f, 0.f}, v1[4] = {0.f, 0.f, 0.f, 0.f};
      const bool have = (cc < 15);
      if (have) {
#pragma unroll
        for (int t = 0; t < 2; ++t) {
          float* v = t ? v1 : v0;
          if (act_[t] && rowok_[t]) {
            const float* base = x + (((size_t)(n * 256 + (cc + 1) * 16 + ic_[t]) * 64 + ghg_[t]) * 64);
            if (al_[t]) {
              const f32x4v fv = *(const f32x4v*)(base + gw0_[t]);
#pragma unroll
              for (int e = 0; e < 4; ++e) v[e] = fv[e];
            } else {
#pragma unroll
              for (int e = 0; e < 4; ++e) {
                const int gwe = gw0_[t] + e;
                v[e] = (gwe >= 0 && gwe < 64) ? base[gwe] : 0.f;
              }
            }
          }
        }
      }

      // MFMA on chunk cc (verbatim R8)
#pragma unroll
      for (int s = 0; s < 4; ++s) {
        if (s < nk0) {
          const bf16x8 A = *(const bf16x8*)(Ab + ((aoff0[s] + cc * 32) ^ swzA));
#pragma unroll
          for (int fg = 0; fg < 4; ++fg) {
            if (fg < nfg0) {
              const bf16x8 B = *(const bf16x8*)(xr + bcell0[fg][s] * 32 + q * 16);
              acc[fg] = __builtin_amdgcn_mfma_f32_32x32x16_bf16(A, B, acc[fg], 0, 0, 0);
            }
          }
        }
      }
      if (wid == 2) {
        const bf16x8 A = *(const bf16x8*)(Ab + ((aoff1 + cc * 32) ^ swzA));
#pragma unroll
        for (int j = 0; j < 2; ++j) {
          const bf16x8 B = *(const bf16x8*)(xr + bcell1[j] * 32 + q * 16);
          acc[1 + j] = __builtin_amdgcn_mfma_f32_32x32x16_bf16(A, B, acc[1 + j], 0, 0, 0);
        }
      }

      // write staged chunk cc+1
      if (have) {
#pragma unroll
        for (int t = 0; t < 2; ++t) {
          const float* v = t ? v1 : v0;
          if (act_[t]) {
#pragma unroll
            for (int e = 0; e < 4; ++e) {
              const int ww = f4g_[t] * 4 + e - 3;
              if (ww >= 0 && ww < 18)
                xw[(gh_[t] * 18 + ww) * 16 + ic_[t]] = f2bf(v[e]);
            }
          }
        }
      }
      __syncthreads();
    }

    // ---- epilogue: 4 sub-phases of 8 ocs; hl[4][8][10][20] aliases xs ----
    short* hl = (short*)(smem + XS_OFF);
#pragma unroll
    for (int g8 = 0; g8 < 4; ++g8) {
#pragma unroll
      for (int fg = 0; fg < 4; ++fg) {
        if (fg < nfg0 && valid0[fg]) {
#pragma unroll
          for (int jj = 0; jj < 4; ++jj)
            hl[hbase0[fg] + (jj + 4 * q) * 200] = f2bf(acc[fg][4 * g8 + jj]);
        }
      }
      if (wid == 2) {
#pragma unroll
        for (int j = 0; j < 2; ++j) {
          if (valid1[j]) {
#pragma unroll
            for (int jj = 0; jj < 4; ++jj)
              hl[hbase1[j] + (jj + 4 * q) * 200] = f2bf(acc[1 + j][4 * g8 + jj]);
          }
        }
      }
      __syncthreads();

      // FIR: one unit per thread (8 ocl x 16 Yl x 4 g = 512)
      const int g = tid & 3;
      const int Yl = (tid >> 2) & 15;
      const int o8 = tid >> 6;
      float o[8];
#pragma unroll
      for (int xx = 0; xx < 8; ++xx) o[xx] = 0.f;
#pragma unroll
      for (int du = 0; du < 4; ++du) {
        const int ttp = Yl - 1 + du;
        const int py = ttp & 1;
        const int r = py ? ((Yl + du) >> 1) : (ttp >> 1);
        const int baseE = (py * 2) * 1600 + o8 * 200 + r * 20 + 4 * g;
        const int baseO = baseE + 1600;
        const short4v e0 = *(const short4v*)(hl + baseE);
        const short4v e1 = *(const short4v*)(hl + baseE + 4);
        const short4v o0 = *(const short4v*)(hl + baseO);
        const short4v o1 = *(const short4v*)(hl + baseO + 4);
        float E[8], O[8];
#pragma unroll
        for (int i = 0; i < 4; ++i) {
          E[i] = bf2f(e0[i]); E[i + 4] = bf2f(e1[i]);
          O[i] = bf2f(o0[i]); O[i + 4] = bf2f(o1[i]);
        }
        float rx[8];
        rx[0] = 0.25f*O[0] + 0.75f*E[0] + 0.75f*O[1] + 0.25f*E[1];
        rx[1] = 0.25f*E[0] + 0.75f*O[1] + 0.75f*E[1] + 0.25f*O[2];
        rx[2] = 0.25f*O[1] + 0.75f*E[1] + 0.75f*O[2] + 0.25f*E[2];
        rx[3] = 0.25f*E[1] + 0.75f*O[2] + 0.75f*E[2] + 0.25f*O[3];
        rx[4] = 0.25f*O[2] + 0.75f*E[2] + 0.75f*O[3] + 0.25f*E[3];
        rx[5] = 0.25f*E[2] + 0.75f*O[3] + 0.75f*E[3] + 0.25f*O[4];
        rx[6] = 0.25f*O[3] + 0.75f*E[3] + 0.75f*O[4] + 0.25f*E[4];
        rx[7] = 0.25f*E[3] + 0.75f*O[4] + 0.75f*E[4] + 0.25f*O[5];
        const float ky = kf4[du];
#pragma unroll
        for (int xx = 0; xx < 8; ++xx) o[xx] += ky * rx[xx];
      }
      const int oc = octile * 32 + g8 * 8 + o8;
      const int Y = atile * 16 + Yl;
      const int X0 = btile * 32 + g * 8;
      float* op = out + (((size_t)(n * 256 + oc)) * 128 + Y) * 128 + X0;
      f32x4v w0, w1;
      w0[0] = o[0]; w0[1] = o[1]; w0[2] = o[2]; w0[3] = o[3];
      w1[0] = o[4]; w1[1] = o[5]; w1[2] = o[6]; w1[3] = o[7];
      *(f32x4v*)op = w0;
      *(f32x4v*)(op + 4) = w1;
      __syncthreads();  // hl free for next sub-phase / next rep's xs staging
    }
  }
}

extern "C" void kernel_launch(void* const* d_in, const int* in_sizes, int n_in,
                              void* d_out, int out_size, void* d_ws, size_t ws_size,
                              hipStream_t stream) {
  (void)in_sizes; (void)n_in; (void)out_size; (void)d_ws; (void)ws_size;
  const float* x = (const float*)d_in[0];
  const float* w = (const float*)d_in[1];
  float* out = (float*)d_out;
  // grid = 8 octiles x 4 n x 8 atiles = 256 blocks (1/CU), 512 threads
  hipLaunchKernelGGL(fir_up_v11, dim3(256), dim3(512), 0, stream, x, w, out);
}